// Round 17
// baseline (261.411 us; speedup 1.0000x reference)
//
#include <hip/hip_runtime.h>

// ---------- types ----------
typedef __attribute__((ext_vector_type(4))) float f32x4;
typedef __attribute__((ext_vector_type(8))) __bf16 bf16x8;
typedef __attribute__((ext_vector_type(4))) unsigned short u16x4;
typedef __attribute__((ext_vector_type(8))) unsigned short u16x8;

#define NB 4096      // batch
#define ND 512       // input dim
#define NH 2048      // mlp hidden
#define NO 512       // output dim

// ---------- helpers ----------
__device__ __forceinline__ unsigned short f2bf(float f) {
  unsigned int u = __float_as_uint(f);
  u += 0x7fffu + ((u >> 16) & 1u);          // RNE
  return (unsigned short)(u >> 16);
}
__device__ __forceinline__ float bf2f(unsigned short u) {
  return __uint_as_float(((unsigned int)u) << 16);
}
__device__ __forceinline__ void gload_lds16(const void* g, void* l) {
  __builtin_amdgcn_global_load_lds(
      (const __attribute__((address_space(1))) unsigned int*)g,
      (__attribute__((address_space(3))) unsigned int*)l, 16, 0, 0);
}
// B-operand pack (LDS-staged): [kt32][Mtot][32], chunk swizzled c^((row>>1)&3)
// (swizzle baked at PACK time so staging reads are fully linear).
__device__ __forceinline__ size_t paddr(int row, int k, int Mtot) {
  int kt = k >> 5, c = (k >> 3) & 3, el = k & 7;
  return ((size_t)kt * Mtot + row) * 32 + (size_t)((c ^ ((row >> 1) & 3)) * 8 + el);
}
// A-operand pack (register-direct, NO LDS): [kt32][fc 0..3][row][8 elems].
// af fragment load = 16 lanes x 16B contiguous (fully coalesced); no swizzle.
__device__ __forceinline__ size_t paddrA(int row, int k, int Mtot) {
  int kt = k >> 5, fc = (k >> 3) & 3, el = k & 7;
  return (((size_t)kt * 4 + fc) * Mtot + row) * 8 + el;
}

// ---------- gating ----------
__global__ void gate_kernel(const float* __restrict__ x, const float* __restrict__ emask,
                            const float* __restrict__ gw, const float* __restrict__ gb,
                            float* __restrict__ w_out, float* __restrict__ mask_out) {
  int b = blockIdx.x;
  int lane = threadIdx.x;
  float l8[8] = {0,0,0,0,0,0,0,0};
  const float* xr = x + (size_t)b * ND;
  for (int d = lane; d < ND; d += 64) {
    float xv = xr[d];
    const float* g = gw + d * 8;
#pragma unroll
    for (int e = 0; e < 8; ++e) l8[e] = fmaf(xv, g[e], l8[e]);
  }
#pragma unroll
  for (int off = 32; off > 0; off >>= 1) {
#pragma unroll
    for (int e = 0; e < 8; ++e) l8[e] += __shfl_xor(l8[e], off);
  }
  float m = -1e30f;
#pragma unroll
  for (int e = 0; e < 8; ++e) { l8[e] += gb[e]; m = fmaxf(m, l8[e]); }
  float s = 0.f, p[8];
#pragma unroll
  for (int e = 0; e < 8; ++e) { p[e] = expf(l8[e] - m); s += p[e]; }
  float inv = 1.f / s;
  float mk[8], me[8], ms = 0.f;
#pragma unroll
  for (int e = 0; e < 8; ++e) {
    mk[e] = emask[(size_t)b * 8 + e];
    me[e] = p[e] * inv * mk[e];
    ms += me[e];
  }
  float winv = 1.f / (ms + 1e-9f);
  if (lane == 0) {
#pragma unroll
    for (int e = 0; e < 8; ++e) {
      w_out[(size_t)b * 8 + e] = me[e] * winv;
      mask_out[(size_t)b * 8 + e] = mk[e];
    }
  }
}

// ---------- cast x to bf16, A-packed ----------
__global__ void cast_x_kernel(const float* __restrict__ x, unsigned short* __restrict__ xb) {
  size_t t = (size_t)blockIdx.x * 256 + threadIdx.x;   // one 8-elem chunk each
  int b = (int)(t >> 6);
  int k0 = ((int)t & 63) * 8;
  const f32x4* px = (const f32x4*)(x + (size_t)b * ND + k0);
  f32x4 v0 = px[0], v1 = px[1];
  u16x8 r;
#pragma unroll
  for (int j = 0; j < 4; ++j) { r[j] = f2bf(v0[j]); r[4 + j] = f2bf(v1[j]); }
  *(u16x8*)(xb + paddrA(b, k0, NB)) = r;
}

// ---------- B-spline basis, A-packed ----------
__global__ void basis_kernel(const float* __restrict__ x, unsigned short* __restrict__ bas) {
  size_t t = (size_t)blockIdx.x * 256 + threadIdx.x;   // = b*512 + i
  int b = (int)(t >> 9);
  int i = (int)(t & 511);
  float xv = x[t];
  const float hg = 0.4f;
  float tt[12];
#pragma unroll
  for (int j = 0; j < 12; ++j) tt[j] = -2.2f + hg * (float)j;
  float b0[11];
#pragma unroll
  for (int j = 0; j < 11; ++j) b0[j] = (tt[j] <= xv && xv < tt[j + 1]) ? 1.f : 0.f;
  float b1[10], b2[9], b3[8];
#pragma unroll
  for (int j = 0; j < 10; ++j) b1[j] = ((xv - tt[j]) * b0[j] + (tt[j + 2] - xv) * b0[j + 1]) * (1.f / (1.f * hg));
#pragma unroll
  for (int j = 0; j < 9; ++j)  b2[j] = ((xv - tt[j]) * b1[j] + (tt[j + 3] - xv) * b1[j + 1]) * (1.f / (2.f * hg));
#pragma unroll
  for (int j = 0; j < 8; ++j)  b3[j] = ((xv - tt[j]) * b2[j] + (tt[j + 4] - xv) * b2[j + 1]) * (1.f / (3.f * hg));
  u16x8 r;
#pragma unroll
  for (int j = 0; j < 8; ++j) r[j] = f2bf(b3[j]);
  *(u16x8*)(bas + paddrA(b, i * 8, NB)) = r;
}

// ---------- transpose+cast: f32 [E][R][Cc] -> B-packed [Cc rows][R k] ----------
__global__ void transpose_cast(const float* __restrict__ in, unsigned short* __restrict__ outp,
                               int R, int Cc) {
  __shared__ float tile[32][33];
  int e = blockIdx.z;
  int c0 = blockIdx.x * 32, r0 = blockIdx.y * 32;
  int tx = threadIdx.x & 31, ty = threadIdx.x >> 5;   // 32 x 8
  const float* ine = in + (size_t)e * R * Cc;
  unsigned short* oute = outp + (size_t)e * R * Cc;
#pragma unroll
  for (int j = 0; j < 32; j += 8)
    tile[ty + j][tx] = ine[(size_t)(r0 + ty + j) * Cc + (c0 + tx)];
  __syncthreads();
#pragma unroll
  for (int j = 0; j < 32; j += 8)
    oute[paddr(c0 + ty + j, r0 + tx, Cc)] = f2bf(tile[tx][ty + j]);
}

// ---------- ceff = coeff*scaling, B-packed [512 rows][4096 k] per expert ----------
__global__ void make_cefft(const float* __restrict__ coeff, const float* __restrict__ scal,
                           unsigned short* __restrict__ outp) {
  size_t t = (size_t)blockIdx.x * 256 + threadIdx.x;  // over 4*512*512, i innermost
  int i = (int)(t & 511);
  int o = (int)((t >> 9) & 511);
  int e = (int)(t >> 18);
  size_t io = ((size_t)e * 512 + i) * 512 + o;
  const f32x4* cp = (const f32x4*)(coeff + io * 8);
  f32x4 c0 = cp[0], c1 = cp[1];
  float s = scal[io];
  u16x8 r;
#pragma unroll
  for (int j = 0; j < 4; ++j) r[j] = f2bf(c0[j] * s);
#pragma unroll
  for (int j = 0; j < 4; ++j) r[4 + j] = f2bf(c1[j] * s);
  *(u16x8*)(outp + (size_t)e * NO * (ND * 8) + paddr(o, i * 8, NO)) = r;
}

// ---------- GEMM args (runtime role selection) ----------
struct GemmArgs {
  const unsigned short* A; size_t sAe; int Ma;   // A-packed [kt32][4][Ma][8]
  const unsigned short* B; size_t sBe; int Mb;   // B-packed [kt32][Mb][32]
  const float* bias; int sBias;
  unsigned short* C; size_t sCe; size_t sHalf; int ldc;
  int Kspan; int zshift; int gx; int nxy;
  int mode;                                       // 0: relu+bias -> A-PACKED C; 2: raw -> row-major C
};

// ---------- GEMM: C[M,N] = A[M,K]*B[N,K]^T, bf16 in/out ----------
// ROUND 17: A-operand bypasses LDS. R15 (best, 45% MfmaUtil) is LDS-pipe
// capped (~50%): 128KB reads + 48KB writes per CU tile-pair vs 1033cy MFMA.
// R16 showed TLP (16 waves/CU) outweighs LDS-traffic relief, and 16 waves is
// the REGISTER ceiling -> keep R15 geometry exactly (BM=128, BN=256, BK=32,
// 8 waves 2Mx4N of 64x64, 2 WGs/CU) and instead move A off the LDS pipe:
// af fragments load DIRECTLY global->reg (A-pack makes them 16 lanes x 16B
// contiguous; 4 N-col waves re-read the same hot 8KB tile via L1/L2).
// LDS now carries only B: 48KB/tile-pair-FLOP -> LDS cap lifts to ~100%.
// A-loads have no LDS WAR hazard (global content constant; safe to hoist);
// compiler auto-inserts the af->MFMA vmcnt (it tracks gload_lds too).
// B ring-3 ledger: 2 gloads/tile; prologue stages t0,t1, vmcnt(2); per tile:
// af loads + B ds_reads -> stage B(t+2) -> MFMA -> vmcnt(2) [t+1 landed,
// t+2 in flight] -> barrier. No mid-tile barrier (drifting waves, R13/R15).
__global__ __launch_bounds__(512, 2) void gemm_fused(int nL1, GemmArgs a1, GemmArgs a2) {
  __shared__ __align__(16) char ls[3 * 16384];
  const int wg = blockIdx.x;
  const GemmArgs g = (wg < nL1) ? a1 : a2;
  const int wgl = (wg < nL1) ? wg : wg - nL1;
  const int tid = threadIdx.x;
  const int lane = tid & 63, wid = tid >> 6;
  const int wr = wid >> 2, wc = wid & 3;           // 2M x 4N waves, 64x64 each
  const int z = wgl / g.nxy;
  int rem = wgl % g.nxy;
  rem = (rem & 7) * (g.nxy >> 3) + (rem >> 3);     // bijective %8 swizzle (nxy%8==0)
  const int bcol = (rem % g.gx) * 256;
  const int brow = (rem / g.gx) * 128;
  const int e = z >> g.zshift;
  const int half = z & ((1 << g.zshift) - 1);
  const int ktBase = half * (g.Kspan >> 5);        // kt32 units
  const unsigned short* Ae = g.A + (size_t)e * g.sAe;
  const unsigned short* Be = g.B + (size_t)e * g.sBe;
  const int Ma = g.Ma, Mb = g.Mb;
  const int NT = g.Kspan >> 5;

  const int fr = lane & 15, fc = lane >> 4;

  // B-only staging: 2 fully-linear 8KB gloads per tile
  auto stage = [&](int buf, int t2) {
    const char* sb = (const char*)Be + ((size_t)(ktBase + t2) * Mb + bcol) * 64;
    gload_lds16(sb + tid * 16, ls + buf * 16384 + tid * 16);
    gload_lds16(sb + 8192 + tid * 16, ls + buf * 16384 + 8192 + tid * 16);
  };
  // A fragment base for this lane: row = brow + wr*64 + fr, chunk fc
  const unsigned short* Abase = Ae + (((size_t)ktBase * 4 + fc) * Ma + (brow + wr * 64 + fr)) * 8;
  const size_t aktStride = (size_t)4 * Ma * 8;     // advance one kt32

  f32x4 acc[4][4] = {};

  // prologue: stage B for tiles 0,1; wait tile0 only (tile1's 2 in flight)
  stage(0, 0);
  stage(1, 1);
  asm volatile("s_waitcnt vmcnt(2)" ::: "memory");
  __builtin_amdgcn_s_barrier();

  int bi = 0;
  for (int t = 0; t < NT; ++t) {
    const char* bB = ls + bi * 16384;
    const int pb = (bi == 0) ? 2 : bi - 1;       // == (t+2) % 3
    const bool pf = (t + 2 < NT);

    bf16x8 af[4], bfrag[4];
    const unsigned short* ap = Abase + (size_t)t * aktStride;
#pragma unroll
    for (int i = 0; i < 4; ++i)
      af[i] = *(const bf16x8*)(ap + (size_t)(i * 16) * 8);   // rows i*16 apart
#pragma unroll
    for (int n = 0; n < 4; ++n) {
      int rb = wc * 64 + n * 16 + fr;
      bfrag[n] = *(const bf16x8*)(bB + rb * 64 + ((fc ^ ((rb >> 1) & 3)) << 4));
    }
    if (pf) stage(pb, t + 2);
    // no mid-tile barrier: waves drift; compiler emits fine-grained waits
    // for af (vmcnt) and bfrag (lgkmcnt) -> MFMA deps.
#pragma unroll
    for (int mi = 0; mi < 4; ++mi)
#pragma unroll
      for (int ni = 0; ni < 4; ++ni)
        acc[mi][ni] = __builtin_amdgcn_mfma_f32_16x16x32_bf16(bfrag[ni], af[mi], acc[mi][ni], 0, 0, 0);
    if (pf)               asm volatile("s_waitcnt vmcnt(2)" ::: "memory");  // B(t+1) landed
    else if (t + 1 < NT)  asm volatile("s_waitcnt vmcnt(0)" ::: "memory");
    __builtin_amdgcn_s_barrier();

    bi = (bi == 2) ? 0 : bi + 1;
  }

  // ---- epilogue: thread holds C[row][col0..col0+3] ----
  unsigned short* Ce = g.C + (size_t)e * g.sCe + (size_t)half * g.sHalf;
  const int ldc = g.ldc;
#pragma unroll
  for (int mi = 0; mi < 4; ++mi) {
    int row = brow + wr * 64 + mi * 16 + fr;
#pragma unroll
    for (int ni = 0; ni < 4; ++ni) {
      int col0 = bcol + wc * 64 + ni * 16 + (fc << 2);
      u16x4 r;
      if (g.mode == 0) {
        f32x4 bv = *(const f32x4*)(g.bias + e * g.sBias + col0);
#pragma unroll
        for (int j = 0; j < 4; ++j) r[j] = f2bf(fmaxf(acc[mi][ni][j] + bv[j], 0.f));
        *(u16x4*)(Ce + paddrA(row, col0, NB)) = r;      // A-packed (consumed as L2's A)
      } else {
#pragma unroll
        for (int j = 0; j < 4; ++j) r[j] = f2bf(acc[mi][ni][j]);
        *(u16x4*)(Ce + (size_t)row * ldc + col0) = r;   // row-major (combine input)
      }
    }
  }
}

// ---------- final weighted combine: sums split-K partials + bias ----------
__global__ void combine_kernel(const unsigned short* __restrict__ eoM,
                               const unsigned short* __restrict__ eoK,
                               const float* __restrict__ b2,
                               const float* __restrict__ w, float* __restrict__ out) {
  int b = blockIdx.x;
  int o = threadIdx.x * 4;
  float wv[8];
#pragma unroll
  for (int e = 0; e < 8; ++e) wv[e] = w[(size_t)b * 8 + e];
  f32x4 acc = {0.f, 0.f, 0.f, 0.f};
#pragma unroll
  for (int e = 0; e < 4; ++e) {
    u16x4 m0 = *(const u16x4*)(eoM + ((size_t)e * NB + b) * NO + o);
    u16x4 m1 = *(const u16x4*)(eoM + ((size_t)(4 + e) * NB + b) * NO + o);
    f32x4 bb = *(const f32x4*)(b2 + e * NO + o);
#pragma unroll
    for (int j = 0; j < 4; ++j)
      acc[j] = fmaf(wv[e], bf2f(m0[j]) + bf2f(m1[j]) + bb[j], acc[j]);
  }
#pragma unroll
  for (int e = 0; e < 4; ++e) {
    u16x4 k0 = *(const u16x4*)(eoK + ((size_t)e * NB + b) * NO + o);
    u16x4 k1 = *(const u16x4*)(eoK + ((size_t)(4 + e) * NB + b) * NO + o);
#pragma unroll
    for (int j = 0; j < 4; ++j)
      acc[j] = fmaf(wv[4 + e], bf2f(k0[j]) + bf2f(k1[j]), acc[j]);
  }
  *(f32x4*)(out + (size_t)b * NO + o) = acc;
}

// ---------- launch ----------
extern "C" void kernel_launch(void* const* d_in, const int* in_sizes, int n_in,
                              void* d_out, int out_size, void* d_ws, size_t ws_size,
                              hipStream_t stream) {
  (void)in_sizes; (void)n_in; (void)out_size;
  const float* x      = (const float*)d_in[0];
  const float* emask  = (const float*)d_in[1];
  const float* gate_w = (const float*)d_in[2];
  const float* gate_b = (const float*)d_in[3];
  const float* mlp_w1 = (const float*)d_in[4];
  const float* mlp_b1 = (const float*)d_in[5];
  const float* mlp_w2 = (const float*)d_in[6];
  const float* mlp_b2 = (const float*)d_in[7];
  const float* kan_s  = (const float*)d_in[8];
  const float* kan_c  = (const float*)d_in[9];

  float* out = (float*)d_out;
  float* mask_out = out + (size_t)NB * NO;
  float* w_out    = mask_out + (size_t)NB * 8;

  char* ws = (char*)d_ws;
  size_t off = 0;
  auto take = [&](size_t bytes) { size_t r = off; off += (bytes + 255) & ~(size_t)255; return r; };
  unsigned short* w1t   = (unsigned short*)(ws + take((size_t)4 * NH * ND * 2));       // 8.39 MB
  unsigned short* w2t   = (unsigned short*)(ws + take((size_t)4 * NO * NH * 2));       // 8.39 MB
  unsigned short* cefft = (unsigned short*)(ws + take((size_t)4 * NO * (ND * 8) * 2)); // 16.78 MB
  unsigned short* xbf   = (unsigned short*)(ws + take((size_t)NB * ND * 2));           // 4.19 MB
  unsigned short* regA  = (unsigned short*)(ws + take((size_t)8 * NB * NO * 2));       // 33.55 MB
  unsigned short* hbuf  = (unsigned short*)(ws + take((size_t)4 * NB * NH * 2));       // 67.11 MB
  size_t base_need = off;                                                              // ~138.4 MB
  size_t eoK_off = base_need;
  const bool fused = (ws_size >= base_need + (size_t)8 * NB * NO * 2);
  unsigned short* eoM = regA;
  unsigned short* bas, *eoK;
  if (fused) {
    bas = regA;                                              // basis lives in regA pre-L2
    eoK = (unsigned short*)(ws + eoK_off);                   // 33.55 MB tail
  } else {
    bas = hbuf;                                              // fallback aliases
    eoK = (unsigned short*)((char*)hbuf + (size_t)2 * NB * NH * 2);
  }

  gate_kernel<<<NB, 64, 0, stream>>>(x, emask, gate_w, gate_b, w_out, mask_out);
  cast_x_kernel<<<(NB * ND / 8) / 256, 256, 0, stream>>>(x, xbf);
  transpose_cast<<<dim3(NH / 32, ND / 32, 4), 256, 0, stream>>>(mlp_w1, w1t, ND, NH);
  transpose_cast<<<dim3(NO / 32, NH / 32, 4), 256, 0, stream>>>(mlp_w2, w2t, NH, NO);
  make_cefft<<<(4 * ND * NO) / 256, 256, 0, stream>>>(kan_c, kan_s, cefft);

  // per-z grids: BM=128 rows, BN=256 cols (identical tiling to R15)
  GemmArgs aL1 = { xbf, 0, NB,
                   w1t, (size_t)NH * ND, NH,
                   mlp_b1, NH,
                   hbuf, (size_t)NB * NH, 0, NH,
                   ND, 0, NH / 256, (NH / 256) * (NB / 128), 0 };     // nxy = 256
  GemmArgs aL2 = { hbuf, (size_t)NB * NH, NB,
                   w2t, (size_t)NO * NH, NO,
                   nullptr, 0,
                   eoM, (size_t)NB * NO, (size_t)4 * NB * NO, NO,
                   NH / 2, 1, NO / 256, (NO / 256) * (NB / 128), 2 }; // nxy = 64
  GemmArgs aL3 = { bas, 0, NB,
                   cefft, (size_t)NO * (ND * 8), NO,
                   nullptr, 0,
                   eoK, (size_t)NB * NO, (size_t)4 * NB * NO, NO,
                   (ND * 8) / 2, 1, NO / 256, (NO / 256) * (NB / 128), 2 }; // nxy = 64

  const int nL1 = 4 * ((NH / 256) * (NB / 128));    // 1024
  const int nL2 = 8 * ((NO / 256) * (NB / 128));    // 512
  const int nL3 = 8 * ((NO / 256) * (NB / 128));    // 512

  if (fused) {
    basis_kernel<<<(NB * ND) / 256, 256, 0, stream>>>(x, bas);
    gemm_fused<<<nL1 + nL3, 512, 0, stream>>>(nL1, aL1, aL3);
    gemm_fused<<<nL2, 512, 0, stream>>>(0, aL2, aL2);
  } else {
    gemm_fused<<<nL1, 512, 0, stream>>>(nL1, aL1, aL1);
    gemm_fused<<<nL2, 512, 0, stream>>>(0, aL2, aL2);
    basis_kernel<<<(NB * ND) / 256, 256, 0, stream>>>(x, bas);
    gemm_fused<<<nL3, 512, 0, stream>>>(0, aL3, aL3);
  }

  combine_kernel<<<NB, NO / 4, 0, stream>>>(eoM, eoK, mlp_b2, w_out, out);
}

// Round 18
// 211.444 us; speedup vs baseline: 1.2363x; 1.2363x over previous
//
#include <hip/hip_runtime.h>

// ---------- types ----------
typedef __attribute__((ext_vector_type(4))) float f32x4;
typedef __attribute__((ext_vector_type(8))) __bf16 bf16x8;
typedef __attribute__((ext_vector_type(4))) unsigned short u16x4;
typedef __attribute__((ext_vector_type(8))) unsigned short u16x8;

#define NB 4096      // batch
#define ND 512       // input dim
#define NH 2048      // mlp hidden
#define NO 512       // output dim

// ---------- helpers ----------
__device__ __forceinline__ unsigned short f2bf(float f) {
  unsigned int u = __float_as_uint(f);
  u += 0x7fffu + ((u >> 16) & 1u);          // RNE
  return (unsigned short)(u >> 16);
}
__device__ __forceinline__ float bf2f(unsigned short u) {
  return __uint_as_float(((unsigned int)u) << 16);
}
__device__ __forceinline__ void gload_lds16(const void* g, void* l) {
  __builtin_amdgcn_global_load_lds(
      (const __attribute__((address_space(1))) unsigned int*)g,
      (__attribute__((address_space(3))) unsigned int*)l, 16, 0, 0);
}
// K-tile-packed bf16 element index: [kt32][Mtot][32], chunk swizzled c^((row>>1)&3)
// (swizzle baked at PACK time so GEMM staging reads are fully linear).
__device__ __forceinline__ size_t paddr(int row, int k, int Mtot) {
  int kt = k >> 5, c = (k >> 3) & 3, el = k & 7;
  return ((size_t)kt * Mtot + row) * 32 + (size_t)((c ^ ((row >> 1) & 3)) * 8 + el);
}

// ---------- gating ----------
__global__ void gate_kernel(const float* __restrict__ x, const float* __restrict__ emask,
                            const float* __restrict__ gw, const float* __restrict__ gb,
                            float* __restrict__ w_out, float* __restrict__ mask_out) {
  int b = blockIdx.x;
  int lane = threadIdx.x;
  float l8[8] = {0,0,0,0,0,0,0,0};
  const float* xr = x + (size_t)b * ND;
  for (int d = lane; d < ND; d += 64) {
    float xv = xr[d];
    const float* g = gw + d * 8;
#pragma unroll
    for (int e = 0; e < 8; ++e) l8[e] = fmaf(xv, g[e], l8[e]);
  }
#pragma unroll
  for (int off = 32; off > 0; off >>= 1) {
#pragma unroll
    for (int e = 0; e < 8; ++e) l8[e] += __shfl_xor(l8[e], off);
  }
  float m = -1e30f;
#pragma unroll
  for (int e = 0; e < 8; ++e) { l8[e] += gb[e]; m = fmaxf(m, l8[e]); }
  float s = 0.f, p[8];
#pragma unroll
  for (int e = 0; e < 8; ++e) { p[e] = expf(l8[e] - m); s += p[e]; }
  float inv = 1.f / s;
  float mk[8], me[8], ms = 0.f;
#pragma unroll
  for (int e = 0; e < 8; ++e) {
    mk[e] = emask[(size_t)b * 8 + e];
    me[e] = p[e] * inv * mk[e];
    ms += me[e];
  }
  float winv = 1.f / (ms + 1e-9f);
  if (lane == 0) {
#pragma unroll
    for (int e = 0; e < 8; ++e) {
      w_out[(size_t)b * 8 + e] = me[e] * winv;
      mask_out[(size_t)b * 8 + e] = mk[e];
    }
  }
}

// ---------- cast x to bf16, packed ----------
__global__ void cast_x_kernel(const float* __restrict__ x, unsigned short* __restrict__ xb) {
  size_t t = (size_t)blockIdx.x * 256 + threadIdx.x;   // one 8-elem chunk each
  int b = (int)(t >> 6);
  int k0 = ((int)t & 63) * 8;
  const f32x4* px = (const f32x4*)(x + (size_t)b * ND + k0);
  f32x4 v0 = px[0], v1 = px[1];
  u16x8 r;
#pragma unroll
  for (int j = 0; j < 4; ++j) { r[j] = f2bf(v0[j]); r[4 + j] = f2bf(v1[j]); }
  *(u16x8*)(xb + paddr(b, k0, NB)) = r;
}

// ---------- B-spline basis, packed ----------
__global__ void basis_kernel(const float* __restrict__ x, unsigned short* __restrict__ bas) {
  size_t t = (size_t)blockIdx.x * 256 + threadIdx.x;   // = b*512 + i
  int b = (int)(t >> 9);
  int i = (int)(t & 511);
  float xv = x[t];
  const float hg = 0.4f;
  float tt[12];
#pragma unroll
  for (int j = 0; j < 12; ++j) tt[j] = -2.2f + hg * (float)j;
  float b0[11];
#pragma unroll
  for (int j = 0; j < 11; ++j) b0[j] = (tt[j] <= xv && xv < tt[j + 1]) ? 1.f : 0.f;
  float b1[10], b2[9], b3[8];
#pragma unroll
  for (int j = 0; j < 10; ++j) b1[j] = ((xv - tt[j]) * b0[j] + (tt[j + 2] - xv) * b0[j + 1]) * (1.f / (1.f * hg));
#pragma unroll
  for (int j = 0; j < 9; ++j)  b2[j] = ((xv - tt[j]) * b1[j] + (tt[j + 3] - xv) * b1[j + 1]) * (1.f / (2.f * hg));
#pragma unroll
  for (int j = 0; j < 8; ++j)  b3[j] = ((xv - tt[j]) * b2[j] + (tt[j + 4] - xv) * b2[j + 1]) * (1.f / (3.f * hg));
  u16x8 r;
#pragma unroll
  for (int j = 0; j < 8; ++j) r[j] = f2bf(b3[j]);
  *(u16x8*)(bas + paddr(b, i * 8, NB)) = r;
}

// ---------- transpose+cast: f32 [E][R][Cc] -> packed B[Cc rows][R k] ----------
__global__ void transpose_cast(const float* __restrict__ in, unsigned short* __restrict__ outp,
                               int R, int Cc) {
  __shared__ float tile[32][33];
  int e = blockIdx.z;
  int c0 = blockIdx.x * 32, r0 = blockIdx.y * 32;
  int tx = threadIdx.x & 31, ty = threadIdx.x >> 5;   // 32 x 8
  const float* ine = in + (size_t)e * R * Cc;
  unsigned short* oute = outp + (size_t)e * R * Cc;
#pragma unroll
  for (int j = 0; j < 32; j += 8)
    tile[ty + j][tx] = ine[(size_t)(r0 + ty + j) * Cc + (c0 + tx)];
  __syncthreads();
#pragma unroll
  for (int j = 0; j < 32; j += 8)
    oute[paddr(c0 + ty + j, r0 + tx, Cc)] = f2bf(tile[tx][ty + j]);
}

// ---------- ceff = coeff*scaling, packed B[512 rows][4096 k] per expert ----------
__global__ void make_cefft(const float* __restrict__ coeff, const float* __restrict__ scal,
                           unsigned short* __restrict__ outp) {
  size_t t = (size_t)blockIdx.x * 256 + threadIdx.x;  // over 4*512*512, i innermost
  int i = (int)(t & 511);
  int o = (int)((t >> 9) & 511);
  int e = (int)(t >> 18);
  size_t io = ((size_t)e * 512 + i) * 512 + o;
  const f32x4* cp = (const f32x4*)(coeff + io * 8);
  f32x4 c0 = cp[0], c1 = cp[1];
  float s = scal[io];
  u16x8 r;
#pragma unroll
  for (int j = 0; j < 4; ++j) r[j] = f2bf(c0[j] * s);
#pragma unroll
  for (int j = 0; j < 4; ++j) r[4 + j] = f2bf(c1[j] * s);
  *(u16x8*)(outp + (size_t)e * NO * (ND * 8) + paddr(o, i * 8, NO)) = r;
}

// ---------- GEMM args (runtime role selection) ----------
struct GemmArgs {
  const unsigned short* A; size_t sAe; int Ma;   // packed [kt32][Ma][32]
  const unsigned short* B; size_t sBe; int Mb;   // packed [kt32][Mb][32]
  const float* bias; int sBias;
  unsigned short* C; size_t sCe; size_t sHalf; int ldc;
  int Kspan; int zshift; int gx; int nxy;
  int mode;                                       // 0: relu+bias -> PACKED C; 2: raw -> row-major C
};

// ---------- GEMM: C[M,N] = A[M,K]*B[N,K]^T, bf16 in/out ----------
// ROUND 18 = R15 verbatim (the measured optimum of this design family).
// BM=128, BN=256, BK=32, 8 waves (2M x 4N), per-wave 64x64.
// LDS ring-3 x 24KB (A 8KB + B 16KB) = 72KB -> 2 WGs/CU (16 waves, 4/SIMD).
// Co-resident WGs fill each other's stalls (m114). Packed operands (staging
// = 3 fully-linear 8KB gloads), NO mid-tile barrier (waves drift; compiler
// emits fine-grained lgkmcnt for read->MFMA deps), stage-after-reads,
// counted vmcnt(3) at tile end (3 loads/tile, distance-2 ring-3).
// Verdicts from controlled experiments: R16 (fatter waves, less LDS/FLOP)
// regressed -> TLP dominates; R17 (A via global->reg) regressed -> VMEM
// latency dominates; R15 sits at ~90% of its LDS-pipe cap at the register
// ceiling for this accumulator size. This is the family optimum.
__global__ __launch_bounds__(512, 2) void gemm_fused(int nL1, GemmArgs a1, GemmArgs a2) {
  __shared__ __align__(16) char ls[3 * 24576];
  const int wg = blockIdx.x;
  const GemmArgs g = (wg < nL1) ? a1 : a2;
  const int wgl = (wg < nL1) ? wg : wg - nL1;
  const int tid = threadIdx.x;
  const int lane = tid & 63, wid = tid >> 6;
  const int wr = wid >> 2, wc = wid & 3;           // 2M x 4N waves, 64x64 each
  const int z = wgl / g.nxy;
  int rem = wgl % g.nxy;
  rem = (rem & 7) * (g.nxy >> 3) + (rem >> 3);     // bijective %8 swizzle (nxy%8==0)
  const int bcol = (rem % g.gx) * 256;
  const int brow = (rem / g.gx) * 128;
  const int e = z >> g.zshift;
  const int half = z & ((1 << g.zshift) - 1);
  const int ktBase = half * (g.Kspan >> 5);        // kt32 units
  const unsigned short* Ae = g.A + (size_t)e * g.sAe;
  const unsigned short* Be = g.B + (size_t)e * g.sBe;
  const int Ma = g.Ma, Mb = g.Mb;
  const int NT = g.Kspan >> 5;

  const int fr = lane & 15, fc = lane >> 4;

  auto stage = [&](int buf, int t2) {
    const char* sa = (const char*)Ae + ((size_t)(ktBase + t2) * Ma + brow) * 64;
    gload_lds16(sa + tid * 16, ls + buf * 24576 + tid * 16);
    const char* sb = (const char*)Be + ((size_t)(ktBase + t2) * Mb + bcol) * 64;
    gload_lds16(sb + tid * 16, ls + buf * 24576 + 8192 + tid * 16);
    gload_lds16(sb + 8192 + tid * 16, ls + buf * 24576 + 16384 + tid * 16);
  };

  f32x4 acc[4][4] = {};

  // prologue: stage tiles 0,1 (6 loads); wait tile0 only (tile1's 3 in flight)
  stage(0, 0);
  stage(1, 1);
  asm volatile("s_waitcnt vmcnt(3)" ::: "memory");
  __builtin_amdgcn_s_barrier();

  int bi = 0;
  for (int t = 0; t < NT; ++t) {
    const char* bA = ls + bi * 24576;
    const char* bB = bA + 8192;
    const int pb = (bi == 0) ? 2 : bi - 1;       // == (t+2) % 3
    const bool pf = (t + 2 < NT);

    bf16x8 af[4], bfrag[4];
#pragma unroll
    for (int i = 0; i < 4; ++i) {
      int ra = wr * 64 + i * 16 + fr;
      af[i] = *(const bf16x8*)(bA + ra * 64 + ((fc ^ ((ra >> 1) & 3)) << 4));
    }
#pragma unroll
    for (int n = 0; n < 4; ++n) {
      int rb = wc * 64 + n * 16 + fr;
      bfrag[n] = *(const bf16x8*)(bB + rb * 64 + ((fc ^ ((rb >> 1) & 3)) << 4));
    }
    if (pf) stage(pb, t + 2);
    // no mid-tile barrier / lgkmcnt(0) / sched_barrier: waves drift, the 2nd
    // resident WG + drifted waves fill the LDS/MFMA pipes during stalls.
#pragma unroll
    for (int mi = 0; mi < 4; ++mi)
#pragma unroll
      for (int ni = 0; ni < 4; ++ni)
        acc[mi][ni] = __builtin_amdgcn_mfma_f32_16x16x32_bf16(bfrag[ni], af[mi], acc[mi][ni], 0, 0, 0);
    if (pf)               asm volatile("s_waitcnt vmcnt(3)" ::: "memory");  // t+1 landed
    else if (t + 1 < NT)  asm volatile("s_waitcnt vmcnt(0)" ::: "memory");
    __builtin_amdgcn_s_barrier();

    bi = (bi == 2) ? 0 : bi + 1;
  }

  // ---- epilogue: thread holds C[row][col0..col0+3] ----
  unsigned short* Ce = g.C + (size_t)e * g.sCe + (size_t)half * g.sHalf;
  const int ldc = g.ldc;
#pragma unroll
  for (int mi = 0; mi < 4; ++mi) {
    int row = brow + wr * 64 + mi * 16 + fr;
#pragma unroll
    for (int ni = 0; ni < 4; ++ni) {
      int col0 = bcol + wc * 64 + ni * 16 + (fc << 2);
      u16x4 r;
      if (g.mode == 0) {
        f32x4 bv = *(const f32x4*)(g.bias + e * g.sBias + col0);
#pragma unroll
        for (int j = 0; j < 4; ++j) r[j] = f2bf(fmaxf(acc[mi][ni][j] + bv[j], 0.f));
        *(u16x4*)(Ce + paddr(row, col0, NB)) = r;       // packed (consumed as L2's A)
      } else {
#pragma unroll
        for (int j = 0; j < 4; ++j) r[j] = f2bf(acc[mi][ni][j]);
        *(u16x4*)(Ce + (size_t)row * ldc + col0) = r;   // row-major (combine input)
      }
    }
  }
}

// ---------- final weighted combine: sums split-K partials + bias ----------
__global__ void combine_kernel(const unsigned short* __restrict__ eoM,
                               const unsigned short* __restrict__ eoK,
                               const float* __restrict__ b2,
                               const float* __restrict__ w, float* __restrict__ out) {
  int b = blockIdx.x;
  int o = threadIdx.x * 4;
  float wv[8];
#pragma unroll
  for (int e = 0; e < 8; ++e) wv[e] = w[(size_t)b * 8 + e];
  f32x4 acc = {0.f, 0.f, 0.f, 0.f};
#pragma unroll
  for (int e = 0; e < 4; ++e) {
    u16x4 m0 = *(const u16x4*)(eoM + ((size_t)e * NB + b) * NO + o);
    u16x4 m1 = *(const u16x4*)(eoM + ((size_t)(4 + e) * NB + b) * NO + o);
    f32x4 bb = *(const f32x4*)(b2 + e * NO + o);
#pragma unroll
    for (int j = 0; j < 4; ++j)
      acc[j] = fmaf(wv[e], bf2f(m0[j]) + bf2f(m1[j]) + bb[j], acc[j]);
  }
#pragma unroll
  for (int e = 0; e < 4; ++e) {
    u16x4 k0 = *(const u16x4*)(eoK + ((size_t)e * NB + b) * NO + o);
    u16x4 k1 = *(const u16x4*)(eoK + ((size_t)(4 + e) * NB + b) * NO + o);
#pragma unroll
    for (int j = 0; j < 4; ++j)
      acc[j] = fmaf(wv[4 + e], bf2f(k0[j]) + bf2f(k1[j]), acc[j]);
  }
  *(f32x4*)(out + (size_t)b * NO + o) = acc;
}

// ---------- launch ----------
extern "C" void kernel_launch(void* const* d_in, const int* in_sizes, int n_in,
                              void* d_out, int out_size, void* d_ws, size_t ws_size,
                              hipStream_t stream) {
  (void)in_sizes; (void)n_in; (void)out_size;
  const float* x      = (const float*)d_in[0];
  const float* emask  = (const float*)d_in[1];
  const float* gate_w = (const float*)d_in[2];
  const float* gate_b = (const float*)d_in[3];
  const float* mlp_w1 = (const float*)d_in[4];
  const float* mlp_b1 = (const float*)d_in[5];
  const float* mlp_w2 = (const float*)d_in[6];
  const float* mlp_b2 = (const float*)d_in[7];
  const float* kan_s  = (const float*)d_in[8];
  const float* kan_c  = (const float*)d_in[9];

  float* out = (float*)d_out;
  float* mask_out = out + (size_t)NB * NO;
  float* w_out    = mask_out + (size_t)NB * 8;

  char* ws = (char*)d_ws;
  size_t off = 0;
  auto take = [&](size_t bytes) { size_t r = off; off += (bytes + 255) & ~(size_t)255; return r; };
  unsigned short* w1t   = (unsigned short*)(ws + take((size_t)4 * NH * ND * 2));       // 8.39 MB
  unsigned short* w2t   = (unsigned short*)(ws + take((size_t)4 * NO * NH * 2));       // 8.39 MB
  unsigned short* cefft = (unsigned short*)(ws + take((size_t)4 * NO * (ND * 8) * 2)); // 16.78 MB
  unsigned short* xbf   = (unsigned short*)(ws + take((size_t)NB * ND * 2));           // 4.19 MB
  unsigned short* regA  = (unsigned short*)(ws + take((size_t)8 * NB * NO * 2));       // 33.55 MB
  unsigned short* hbuf  = (unsigned short*)(ws + take((size_t)4 * NB * NH * 2));       // 67.11 MB
  size_t base_need = off;                                                              // ~138.4 MB
  size_t eoK_off = base_need;
  const bool fused = (ws_size >= base_need + (size_t)8 * NB * NO * 2);
  unsigned short* eoM = regA;
  unsigned short* bas, *eoK;
  if (fused) {
    bas = regA;                                              // basis lives in regA pre-L2
    eoK = (unsigned short*)(ws + eoK_off);                   // 33.55 MB tail
  } else {
    bas = hbuf;                                              // fallback aliases
    eoK = (unsigned short*)((char*)hbuf + (size_t)2 * NB * NH * 2);
  }

  gate_kernel<<<NB, 64, 0, stream>>>(x, emask, gate_w, gate_b, w_out, mask_out);
  cast_x_kernel<<<(NB * ND / 8) / 256, 256, 0, stream>>>(x, xbf);
  transpose_cast<<<dim3(NH / 32, ND / 32, 4), 256, 0, stream>>>(mlp_w1, w1t, ND, NH);
  transpose_cast<<<dim3(NO / 32, NH / 32, 4), 256, 0, stream>>>(mlp_w2, w2t, NH, NO);
  make_cefft<<<(4 * ND * NO) / 256, 256, 0, stream>>>(kan_c, kan_s, cefft);

  // per-z grids: BM=128 rows, BN=256 cols
  GemmArgs aL1 = { xbf, 0, NB,
                   w1t, (size_t)NH * ND, NH,
                   mlp_b1, NH,
                   hbuf, (size_t)NB * NH, 0, NH,
                   ND, 0, NH / 256, (NH / 256) * (NB / 128), 0 };     // nxy = 256
  GemmArgs aL2 = { hbuf, (size_t)NB * NH, NB,
                   w2t, (size_t)NO * NH, NO,
                   nullptr, 0,
                   eoM, (size_t)NB * NO, (size_t)4 * NB * NO, NO,
                   NH / 2, 1, NO / 256, (NO / 256) * (NB / 128), 2 }; // nxy = 64
  GemmArgs aL3 = { bas, 0, NB,
                   cefft, (size_t)NO * (ND * 8), NO,
                   nullptr, 0,
                   eoK, (size_t)NB * NO, (size_t)4 * NB * NO, NO,
                   (ND * 8) / 2, 1, NO / 256, (NO / 256) * (NB / 128), 2 }; // nxy = 64

  const int nL1 = 4 * ((NH / 256) * (NB / 128));    // 1024
  const int nL2 = 8 * ((NO / 256) * (NB / 128));    // 512
  const int nL3 = 8 * ((NO / 256) * (NB / 128));    // 512

  if (fused) {
    basis_kernel<<<(NB * ND) / 256, 256, 0, stream>>>(x, bas);
    gemm_fused<<<nL1 + nL3, 512, 0, stream>>>(nL1, aL1, aL3);
    gemm_fused<<<nL2, 512, 0, stream>>>(0, aL2, aL2);
  } else {
    gemm_fused<<<nL1, 512, 0, stream>>>(nL1, aL1, aL1);
    gemm_fused<<<nL2, 512, 0, stream>>>(0, aL2, aL2);
    basis_kernel<<<(NB * ND) / 256, 256, 0, stream>>>(x, bas);
    gemm_fused<<<nL3, 512, 0, stream>>>(0, aL3, aL3);
  }

  combine_kernel<<<NB, NO / 4, 0, stream>>>(eoM, eoK, mlp_b2, w_out, out);
}